// Round 6
// baseline (304.511 us; speedup 1.0000x reference)
//
#include <hip/hip_runtime.h>
#include <math.h>

// B=64, Q=4096, N=256, 20 fg + 1 bg. Output (B,Q,N) fp32 = 268 MB.
// SPARSITY: P(dist<=2) ~ 0.027% -> ~93.5% of wave-iters store constant 1e6
// after a 4-VALU/pair FMA cull (d2 = |p|^2+|t|^2 - 2p.t; error < 0.02 ->
// d2_fma > 4.03 is a certain strict-gate miss). Hit-waves recompute the
// STRICT numpy-order d2 (tc = -0.5*(-2tc) is exact) -> gate bit-identical.
// R6: nontemporal dwordx4 stores (write-once stream, skip L2 residency),
// TQ=128 + slim regs + launch_bounds(256,6) for 6 blocks/CU, g0 prefetch.
#define BQ 64
#define QQ 4096
#define NN 256
#define NC 20
#define NL 21
#define TQ 128          // queries per block
#define GEO_STRIDE 12   // 3x float4 per q, 16-B aligned (ds_read_b128)
#define PROB_STRIDE (TQ + 1)  // 129: staging writes & label gather conflict-free

// Strict gate: sqrt_rn(d2) <= 2.0  <=>  d2 <= 4 + ulp(4).
#define GATE_D2  0x1.000001p+2f
#define CULL_D2  4.03f   // conservative FMA-form cull bound

typedef float v4f __attribute__((ext_vector_type(4)));

__global__ __launch_bounds__(256, 6)
void matcher_kernel(const float* __restrict__ logits,
                    const float* __restrict__ pboxes,
                    const int*   __restrict__ tlabels,
                    const float* __restrict__ tboxes,
                    float* __restrict__ out) {
    __shared__ __align__(16) float geo[TQ * GEO_STRIDE];    // 6 KB
    __shared__ float prob[NC * PROB_STRIDE];                // 10.3 KB -> 16.3 KB total
    const int tid = threadIdx.x;
    const int b   = blockIdx.y;
    const int q0  = blockIdx.x * TQ;

    // ---- staging: threads 0..127 handle one q each (softmax once per q) ----
    if (tid < TQ) {
        const int q = q0 + tid;
        const float* lg = logits + (size_t)(b * QQ + q) * NL;
        float l[NL];
        #pragma unroll
        for (int c = 0; c < NL; ++c) l[c] = lg[c];
        float m = l[0];
        #pragma unroll
        for (int c = 1; c < NL; ++c) m = fmaxf(m, l[c]);
        float e[NL];
        float s = 0.f;
        #pragma unroll
        for (int c = 0; c < NL; ++c) { e[c] = expf(l[c] - m); s += e[c]; }
        const float rs = 1.0f / s;
        #pragma unroll
        for (int c = 0; c < NC; ++c)    // bank (c+tid)%32: conflict-free
            prob[c * PROB_STRIDE + tid] = -(e[c] * rs);

        const float* pb = pboxes + (size_t)(b * QQ + q) * 6;
        const float pcx = pb[0], pcy = pb[1], pcz = pb[2];
        const float psx = pb[3], psy = pb[4], psz = pb[5];
        float4* gp = (float4*)(geo + tid * GEO_STRIDE);
        // g0 = (pc.xyz, |pc|^2)  g1 = (min1.xyz, vol1)  g2 = (max1.xyz, 0)
        gp[0] = make_float4(pcx, pcy, pcz, pcx * pcx + pcy * pcy + pcz * pcz);
        gp[1] = make_float4(pcx - psx * 0.5f, pcy - psy * 0.5f, pcz - psz * 0.5f,
                            psx * psy * psz);
        gp[2] = make_float4(pcx + psx * 0.5f, pcy + psy * 0.5f, pcz + psz * 0.5f, 0.f);
    }

    // ---- per-thread target state, register-slimmed (~32 VGPRs) ----
    // Keep: -2*tc (exact -> tc recoverable exactly), |tc|^2, sizes, labels.
    const int lane = tid & 63;
    const int w    = tid >> 6;
    const int n0   = lane * 4;
    float n2x[4], n2y[4], n2z[4], t2[4];
    float szx[4], szy[4], szz[4];
    int plab[4];
    #pragma unroll
    for (int j = 0; j < 4; ++j) {
        const float* tb = tboxes + (size_t)(b * NN + n0 + j) * 6;
        const float cx = tb[0], cy = tb[1], cz = tb[2];
        n2x[j] = -2.0f * cx; n2y[j] = -2.0f * cy; n2z[j] = -2.0f * cz;
        t2[j]  = cx * cx + cy * cy + cz * cz;
        szx[j] = tb[3]; szy[j] = tb[4]; szz[j] = tb[5];
        plab[j] = tlabels[b * NN + n0 + j] * PROB_STRIDE;
    }

    __syncthreads();

    const v4f MISS = 1000000.0f;       // broadcast
    float* ob = out + ((size_t)(b * QQ + q0)) * NN + n0;

    // One nontemporal dwordx4 store per wave-iter = contiguous 1-KB q-row.
    // g0 software-prefetched across the branch to hide ds_read latency.
    float4 g0 = *(const float4*)(geo + w * GEO_STRIDE);
    for (int qq = w; qq < TQ; qq += 4) {
        const int qn = (qq + 4) & (TQ - 1);                    // wraps harmlessly
        const float4 g0n = *(const float4*)(geo + qn * GEO_STRIDE);

        int near = 0;
        #pragma unroll
        for (int j = 0; j < 4; ++j) {      // 1 add + 3 fma + 1 cmp per pair
            const float d2f = fmaf(g0.x, n2x[j],
                             fmaf(g0.y, n2y[j],
                             fmaf(g0.z, n2z[j], g0.w + t2[j])));
            near |= (d2f <= CULL_D2);
        }

        v4f* orow = (v4f*)(ob + (size_t)qq * NN);
        if (!__any(near)) {                // ~93.5% of wave-iters
            __builtin_nontemporal_store(MISS, orow);
            g0 = g0n;
            continue;
        }

        // ---- slow path: strict numpy-order d2, bit-exact gate ----
        const float4 g1 = *(const float4*)(geo + qq * GEO_STRIDE + 4);  // min1, vol1
        const float4 g2 = *(const float4*)(geo + qq * GEO_STRIDE + 8);  // max1
        v4f r;
        #pragma unroll
        for (int j = 0; j < 4; ++j) {
            const float tcx = -0.5f * n2x[j];   // exact recovery
            const float tcy = -0.5f * n2y[j];
            const float tcz = -0.5f * n2z[j];
            const float dx = __fsub_rn(g0.x, tcx);
            const float dy = __fsub_rn(g0.y, tcy);
            const float dz = __fsub_rn(g0.z, tcz);
            const float d2 = __fadd_rn(__fadd_rn(__fmul_rn(dx, dx), __fmul_rn(dy, dy)),
                                       __fmul_rn(dz, dz));
            const float negp = prob[plab[j] + qq];
            const float dist = __builtin_amdgcn_sqrtf(d2);   // continuous term only

            const float mnx = tcx - szx[j] * 0.5f, mxx = tcx + szx[j] * 0.5f;
            const float mny = tcy - szy[j] * 0.5f, mxy = tcy + szy[j] * 0.5f;
            const float mnz = tcz - szz[j] * 0.5f, mxz = tcz + szz[j] * 0.5f;
            const float ix = fmaxf(fminf(g2.x, mxx) - fmaxf(g1.x, mnx), 0.f);
            const float iy = fmaxf(fminf(g2.y, mxy) - fmaxf(g1.y, mny), 0.f);
            const float iz = fmaxf(fminf(g2.z, mxz) - fmaxf(g1.z, mnz), 0.f);
            const float iv  = ix * iy * iz;
            const float uni = g1.w + szx[j] * szy[j] * szz[j] - iv;  // > 0 always
            const float iou = iv * __builtin_amdgcn_rcpf(uni);

            const float t = fmaf(5.0f, dist, negp) + fmaf(-2.0f, iou, 2.0f);
            const float rv = (d2 <= GATE_D2) ? t : 1000000.0f;  // bit-exact gate
            if (j == 0) r.x = rv; else if (j == 1) r.y = rv;
            else if (j == 2) r.z = rv; else r.w = rv;
        }
        __builtin_nontemporal_store(r, orow);
        g0 = g0n;
    }
}

extern "C" void kernel_launch(void* const* d_in, const int* in_sizes, int n_in,
                              void* d_out, int out_size, void* d_ws, size_t ws_size,
                              hipStream_t stream) {
    const float* logits  = (const float*)d_in[0];  // (B,Q,21)
    const float* pboxes  = (const float*)d_in[1];  // (B,Q,6)
    const int*   tlabels = (const int*)d_in[2];    // (B,N)
    const float* tboxes  = (const float*)d_in[3];  // (B,N,6)
    float* out = (float*)d_out;                    // (B,Q,N) fp32

    dim3 grid(QQ / TQ, BQ);                        // 32 x 64 = 2048 blocks
    matcher_kernel<<<grid, dim3(256), 0, stream>>>(logits, pboxes, tlabels, tboxes, out);
}

// Round 7
// 295.533 us; speedup vs baseline: 1.0304x; 1.0304x over previous
//
#include <hip/hip_runtime.h>
#include <math.h>

// B=64, Q=4096, N=256, 20 fg classes + 1 bg. Output (B,Q,N) fp32 = 268 MB.
// SPARSITY: centers uniform in [0,50]^3, gate radius 2 -> P(hit) ~ 0.027%;
// P(wave-iter has any hit) ~ 6.5%. Fast path: 4-VALU/pair FMA cull via
// d2 = (|p|^2+|t|^2) - 2 p.t; |d2_fma - d2_strict| < 0.02 (coords<=50 ->
// intermediates<=15000, ulp<=2e-3, <=8 roundings), so d2_fma > 4.03 is a
// certain strict-gate miss. Waves with any d2_fma <= 4.03 recompute the
// STRICT numpy-order d2 and gate bit-exactly (absmax stays 0).
//
// ROOFLINE NOTE (R4-R6 evidence): kernel portion ~60 us vs ~50 us compulsory
// traffic floor (268 MB WO stream + 29 MB in at fill-calibrated 6.0 TB/s).
// R4 (-66% pair VALU) -8us, R5 (-50% cull VALU) +-0, R6 (nt stores, 2x
// occupancy) +9us -> store-drain-bound at achievable BW. R6's nt-store/
// TQ=128 bundle regressed; this is the measured-best R5 structure.
#define BQ 64
#define QQ 4096
#define NN 256
#define NC 20
#define NL 21
#define TQ 256          // queries per block
#define GEO_STRIDE 12   // 3x float4 records, 16-B aligned (ds_read_b128)
#define PROB_STRIDE 257 // label gather distinct banks; staging writes conflict-free

// Strict gate: sqrt_rn(d2) <= 2.0  <=>  d2 <= 4 + ulp(4).
#define GATE_D2  0x1.000001p+2f
#define CULL_D2  4.03f   // conservative FMA-form cull bound

__global__ __launch_bounds__(256)
void matcher_kernel(const float* __restrict__ logits,
                    const float* __restrict__ pboxes,
                    const int*   __restrict__ tlabels,
                    const float* __restrict__ tboxes,
                    float* __restrict__ out) {
    __shared__ __align__(16) float geo[TQ * GEO_STRIDE];    // 12 KB
    __shared__ float prob[NC * PROB_STRIDE];                // 20.1 KB
    const int tid = threadIdx.x;
    const int b   = blockIdx.y;
    const int q0  = blockIdx.x * TQ;

    // ---- staging: one q per thread (softmax once per q) ----
    {
        const int q = q0 + tid;
        const float* lg = logits + (size_t)(b * QQ + q) * NL;
        float l[NL];
        #pragma unroll
        for (int c = 0; c < NL; ++c) l[c] = lg[c];
        float m = l[0];
        #pragma unroll
        for (int c = 1; c < NL; ++c) m = fmaxf(m, l[c]);
        float e[NL];
        float s = 0.f;
        #pragma unroll
        for (int c = 0; c < NL; ++c) { e[c] = expf(l[c] - m); s += e[c]; }
        const float rs = 1.0f / s;
        #pragma unroll
        for (int c = 0; c < NC; ++c)    // bank (c+tid)%32 -> 2 lanes/bank (free)
            prob[c * PROB_STRIDE + tid] = -(e[c] * rs);

        const float* pb = pboxes + (size_t)(b * QQ + q) * 6;
        const float pcx = pb[0], pcy = pb[1], pcz = pb[2];
        const float psx = pb[3], psy = pb[4], psz = pb[5];
        float4* gp = (float4*)(geo + tid * GEO_STRIDE);
        // g0 = (pc.xyz, |pc|^2)  g1 = (min1.xyz, vol1)  g2 = (max1.xyz, 0)
        gp[0] = make_float4(pcx, pcy, pcz, pcx * pcx + pcy * pcy + pcz * pcz);
        gp[1] = make_float4(pcx - psx * 0.5f, pcy - psy * 0.5f, pcz - psz * 0.5f,
                            psx * psy * psz);
        gp[2] = make_float4(pcx + psx * 0.5f, pcy + psy * 0.5f, pcz + psz * 0.5f, 0.f);
    }

    // ---- per-thread: quad of targets n0..n0+3 in registers ----
    const int lane = tid & 63;
    const int w    = tid >> 6;
    const int n0   = lane * 4;
    float tcx[4], tcy[4], tcz[4];          // strict recompute path
    float n2x[4], n2y[4], n2z[4], t2[4];   // FMA cull path: -2*tc, |tc|^2
    float mn_x[4], mn_y[4], mn_z[4], mx_x[4], mx_y[4], mx_z[4], v2[4];
    int plab[4];
    #pragma unroll
    for (int j = 0; j < 4; ++j) {
        const float* tb = tboxes + (size_t)(b * NN + n0 + j) * 6;
        const float cx = tb[0], cy = tb[1], cz = tb[2];
        const float sx = tb[3], sy = tb[4], sz = tb[5];
        tcx[j] = cx; tcy[j] = cy; tcz[j] = cz;
        n2x[j] = -2.0f * cx; n2y[j] = -2.0f * cy; n2z[j] = -2.0f * cz;
        t2[j]  = cx * cx + cy * cy + cz * cz;
        mn_x[j] = cx - sx * 0.5f; mn_y[j] = cy - sy * 0.5f; mn_z[j] = cz - sz * 0.5f;
        mx_x[j] = cx + sx * 0.5f; mx_y[j] = cy + sy * 0.5f; mx_z[j] = cz + sz * 0.5f;
        v2[j]   = sx * sy * sz;
        plab[j] = tlabels[b * NN + n0 + j] * PROB_STRIDE;
    }

    __syncthreads();

    const float4 MISS = make_float4(1000000.0f, 1000000.0f, 1000000.0f, 1000000.0f);
    float* ob = out + ((size_t)(b * QQ + q0)) * NN + n0;

    // One dwordx4 store per wave-iter = contiguous 1-KB q-row (coalesced).
    for (int qq = w; qq < TQ; qq += 4) {
        const float4* gp = (const float4*)(geo + qq * GEO_STRIDE); // uniform broadcast
        const float4 g0 = gp[0];   // pc.xyz, |pc|^2

        int near = 0;
        #pragma unroll
        for (int j = 0; j < 4; ++j) {      // 1 add + 3 fma + 1 cmp per pair
            const float d2f = fmaf(g0.x, n2x[j],
                             fmaf(g0.y, n2y[j],
                             fmaf(g0.z, n2z[j], g0.w + t2[j])));
            near |= (d2f <= CULL_D2);
        }

        float4* orow = (float4*)(ob + (size_t)qq * NN);
        if (!__any(near)) {                // ~93.5% of wave-iters
            *orow = MISS;
            continue;
        }

        // ---- slow path: strict numpy-order d2, bit-exact gate & values ----
        const float4 g1 = gp[1];           // min1.xyz, vol1
        const float4 g2 = gp[2];           // max1.xyz
        float r[4];
        #pragma unroll
        for (int j = 0; j < 4; ++j) {
            const float dx = __fsub_rn(g0.x, tcx[j]);
            const float dy = __fsub_rn(g0.y, tcy[j]);
            const float dz = __fsub_rn(g0.z, tcz[j]);
            const float d2 = __fadd_rn(__fadd_rn(__fmul_rn(dx, dx), __fmul_rn(dy, dy)),
                                       __fmul_rn(dz, dz));
            const float negp = prob[plab[j] + qq];
            const float dist = __builtin_amdgcn_sqrtf(d2);   // continuous term only

            const float ix = fmaxf(fminf(g2.x, mx_x[j]) - fmaxf(g1.x, mn_x[j]), 0.f);
            const float iy = fmaxf(fminf(g2.y, mx_y[j]) - fmaxf(g1.y, mn_y[j]), 0.f);
            const float iz = fmaxf(fminf(g2.z, mx_z[j]) - fmaxf(g1.z, mn_z[j]), 0.f);
            const float iv  = ix * iy * iz;
            const float uni = g1.w + v2[j] - iv;     // > 0 always (sizes >= 0.5)
            const float iou = iv * __builtin_amdgcn_rcpf(uni);

            const float t = fmaf(5.0f, dist, negp) + fmaf(-2.0f, iou, 2.0f);
            r[j] = (d2 <= GATE_D2) ? t : 1000000.0f; // bit-exact strict gate
        }
        *orow = make_float4(r[0], r[1], r[2], r[3]);
    }
}

extern "C" void kernel_launch(void* const* d_in, const int* in_sizes, int n_in,
                              void* d_out, int out_size, void* d_ws, size_t ws_size,
                              hipStream_t stream) {
    const float* logits  = (const float*)d_in[0];  // (B,Q,21)
    const float* pboxes  = (const float*)d_in[1];  // (B,Q,6)
    const int*   tlabels = (const int*)d_in[2];    // (B,N)
    const float* tboxes  = (const float*)d_in[3];  // (B,N,6)
    float* out = (float*)d_out;                    // (B,Q,N) fp32

    dim3 grid(QQ / TQ, BQ);                        // 16 x 64 = 1024 blocks = 4/CU
    matcher_kernel<<<grid, dim3(256), 0, stream>>>(logits, pboxes, tlabels, tboxes, out);
}